// Round 19
// baseline (203.057 us; speedup 1.0000x reference)
//
#include <hip/hip_runtime.h>
#include <hip/hip_fp16.h>

#define N_NODES 50000
#define N_EDGES 800000
#define NBINS   391          // ceil(50000/128), 128 dst nodes per bin
#define CAP     4096         // fixed per-bin capacity (mean 2048, sigma 45)
#define EPB     4096         // edges per block (binA)
#define NBLK_E  ((N_EDGES + EPB - 1) / EPB)
#define NTILE   391          // node tiles for pre1
#define LSTRIDE 129          // LDS [ch][node] stride, conflict-free

// ---------------- pass A: LDS-staged bin scatter (fixed-capacity bins, 512 thr) ----------------
__global__ __launch_bounds__(512) void k_binA(const int* __restrict__ src,
                                              const int* __restrict__ dst,
                                              int* __restrict__ bincur,
                                              int* __restrict__ binned) {
    __shared__ int cnt[NBINS];
    __shared__ int sc[512];
    __shared__ int lpos[NBINS];
    __shared__ int base[NBINS];
    __shared__ int stage[EPB];
    __shared__ unsigned short sbin[EPB];
    int t = threadIdx.x;
    int blkbase = blockIdx.x * EPB;
    int nE = min(EPB, N_EDGES - blkbase);
    for (int i = t; i < NBINS; i += 512) cnt[i] = 0;
    __syncthreads();
    int sv[8], dv[8];
#pragma unroll
    for (int k = 0; k < 8; ++k) {
        int e = blkbase + t + k * 512;
        if (e < N_EDGES) {
            sv[k] = src[e];
            dv[k] = dst[e];
            atomicAdd(&cnt[dv[k] >> 7], 1);
        } else dv[k] = -1;
    }
    __syncthreads();
    sc[t] = (t < NBINS) ? cnt[t] : 0;
    __syncthreads();
    for (int d = 1; d < 512; d <<= 1) {
        int add = (t >= d) ? sc[t - d] : 0;
        __syncthreads();
        sc[t] += add;
        __syncthreads();
    }
    for (int b = t; b < NBINS; b += 512) {
        int excl = sc[b] - cnt[b];
        lpos[b] = excl;
        sc[b] = excl;
        if (cnt[b] > 0) base[b] = b * CAP + atomicAdd(&bincur[b], cnt[b]);
    }
    __syncthreads();
#pragma unroll
    for (int k = 0; k < 8; ++k) {
        if (dv[k] >= 0) {
            int b = dv[k] >> 7;
            int p = atomicAdd(&lpos[b], 1);
            stage[p] = (sv[k] & 0xFFFF) | ((dv[k] & 127) << 16);
            sbin[p] = (unsigned short)b;
        }
    }
    __syncthreads();
    for (int i = t; i < nE; i += 512) {
        int b = sbin[i];
        int pos = base[b] + (i - sc[b]);
        if (pos < (b + 1) * CAP) binned[pos] = stage[i];   // 45-sigma guard
    }
}

// ---------------- fused: binB (counting sort) + pre1 (dual GEMM) ----------------
// pre1 now writes ph as two 32-channel planes (each 3.2 MB: fits per-XCD L2).
__global__ __launch_bounds__(512) void k_binB_pre1(
        const int* __restrict__ bincur, int* __restrict__ binned,
        int* __restrict__ off, unsigned short* __restrict__ deg,
        int* __restrict__ esrc,
        const float* __restrict__ x,
        const float* __restrict__ wl, const float* __restrict__ wr,
        const float* __restrict__ b,
        __half* __restrict__ ph0, __half* __restrict__ ph1,
        float* __restrict__ q) {
    __shared__ float smem[64 * LSTRIDE];
    int t = threadIdx.x;
    int bb = blockIdx.x;
    if (bb < NBINS) {
        int* buf = (int*)smem;
        int* cnt = buf + CAP;
        int* tmp = cnt + 128;
        int* cur = tmp + 128;
        int n0 = bb << 7;
        int seg0 = bb * CAP;
        int n = min(bincur[bb], CAP);
        if (t < 128) cnt[t] = 0;
        __syncthreads();
        for (int i = t; i < n; i += 512) atomicAdd(&cnt[binned[seg0 + i] >> 16], 1);
        __syncthreads();
        int v = (t < 128) ? cnt[t] : 0;
        if (t < 128) tmp[t] = v;
        __syncthreads();
        int val = v;
        for (int d = 1; d < 128; d <<= 1) {
            int add = (t >= d && t < 128) ? tmp[t - d] : 0;
            __syncthreads();
            if (t < 128) { val += add; tmp[t] = val; }
            __syncthreads();
        }
        if (t < 128) {
            int excl = val - v;
            cur[t] = excl;
            int node = n0 + t;
            if (node < N_NODES) {
                off[node] = seg0 + excl;
                deg[node] = (unsigned short)v;
            }
        }
        __syncthreads();
        for (int i = t; i < n; i += 512) {
            int w = binned[seg0 + i];
            int p = atomicAdd(&cur[w >> 16], 1);
            buf[p] = w & 0xFFFF;
        }
        __syncthreads();
        for (int i = t; i < n; i += 512) esrc[seg0 + i] = buf[i];
        return;
    }
    // ---- pre1 path ----
    float* sx = smem;
    int g0 = (bb - NBINS) * 128;
#pragma unroll
    for (int i = 0; i < 4; ++i) {
        int f = t + i * 512;
        int nd = f >> 4, cq = f & 15;
        int gn = g0 + nd;
        float4 v = (gn < N_NODES) ? ((const float4*)x)[(size_t)gn * 16 + cq]
                                  : make_float4(0.f, 0.f, 0.f, 0.f);
        sx[(cq * 4 + 0) * LSTRIDE + nd] = v.x;
        sx[(cq * 4 + 1) * LSTRIDE + nd] = v.y;
        sx[(cq * 4 + 2) * LSTRIDE + nd] = v.z;
        sx[(cq * 4 + 3) * LSTRIDE + nd] = v.w;
    }
    __syncthreads();
    int role = __builtin_amdgcn_readfirstlane(t >> 7);
    int wsel = role >> 1;
    int c0 = (role & 1) * 32;
    int ln = t & 127;
    int node = g0 + ln;
    const float* __restrict__ wm = wsel ? wr : wl;
    float acc[32];
    if (wsel) {
#pragma unroll
        for (int c = 0; c < 32; ++c) acc[c] = b[c0 + c];
    } else {
#pragma unroll
        for (int c = 0; c < 32; ++c) acc[c] = 0.f;
    }
#pragma unroll
    for (int k = 0; k < 64; ++k) {
        float xk = sx[k * LSTRIDE + ln];
#pragma unroll
        for (int c = 0; c < 32; ++c)
            acc[c] = fmaf(xk, wm[k * 64 + c0 + c], acc[c]);
    }
    if (node >= N_NODES) return;
    if (wsel == 0) {
        alignas(16) __half2 hv[16];
#pragma unroll
        for (int i = 0; i < 16; ++i)
            hv[i] = __floats2half2_rn(acc[2 * i], acc[2 * i + 1]);
        __half* plane = c0 ? ph1 : ph0;                 // 32-ch plane
        float4* op = (float4*)(plane + (size_t)node * 32);
#pragma unroll
        for (int i = 0; i < 4; ++i) op[i] = ((float4*)hv)[i];
    } else {
        float4* op = (float4*)(q + (size_t)node * 64 + c0);
#pragma unroll
        for (int i = 0; i < 8; ++i)
            op[i] = make_float4(acc[4 * i], acc[4 * i + 1], acc[4 * i + 2], acc[4 * i + 3]);
    }
}

// dequant-accumulate 16B of halfs into 8 fp32 accs
__device__ __forceinline__ void acc8(float* a, float4 rv) {
    const __half2* hp = (const __half2*)&rv;
    float2 f0 = __half22float2(hp[0]), f1 = __half22float2(hp[1]);
    float2 f2 = __half22float2(hp[2]), f3 = __half22float2(hp[3]);
    a[0] += f0.x; a[1] += f0.y; a[2] += f1.x; a[3] += f1.y;
    a[4] += f2.x; a[5] += f2.y; a[6] += f3.x; a[7] += f3.y;
}

// ---------------- fused agg1 + pre2: one block per 128-node bin ----------------
// Gather in TWO CHANNEL-PLANE PHASES (each plane 3.2 MB -> per-XCD L2 resident):
// per phase, half-wave per node, eg = 0..7 edge slots x cg = 0..3 16B groups on
// 64 B plane rows; barrier between phases for temporal locality.
// GEMM phase unchanged (wave-uniform SGPR weights on the LDS h1 tile).
__global__ __launch_bounds__(1024) void k_agg1_pre2(
        const int* __restrict__ off, const unsigned short* __restrict__ deg,
        const int* __restrict__ esrc,
        const __half* __restrict__ ph0, const __half* __restrict__ ph1,
        const float* __restrict__ q,
        const float* __restrict__ w2l, const float* __restrict__ w2r,
        const float* __restrict__ b2,
        __half* __restrict__ zh, float* __restrict__ r) {
    __shared__ float sx[64 * LSTRIDE];    // 33 KB h1 tile
    int t = threadIdx.x;
    int n0 = blockIdx.x << 7;
    int half = t >> 5;                    // 0..31 half-wave id
    int l32 = t & 31;
    int eg = l32 >> 2;                    // 0..7 edge slots
    int cg = l32 & 3;                     // 16B group within 32-ch plane row
#pragma unroll
    for (int phase = 0; phase < 2; ++phase) {
        const __half* pp = phase ? ph1 : ph0;
        for (int p = 0; p < 4; ++p) {
            int nl = half + 32 * p;       // 0..127
            int node = n0 + nl;
            if (node < N_NODES) {
                int s0 = off[node];
                int dv = deg[node];
                int s1 = s0 + dv;
                float a0[8] = {0,0,0,0,0,0,0,0}, a1[8] = {0,0,0,0,0,0,0,0};
                for (int i = s0; i < s1; i += 16) {
                    int i0 = i + eg, i1 = i + 8 + eg;
                    if (i0 < s1) acc8(a0, *(const float4*)(pp + (size_t)esrc[i0] * 32 + (cg << 3)));
                    if (i1 < s1) acc8(a1, *(const float4*)(pp + (size_t)esrc[i1] * 32 + (cg << 3)));
                }
#pragma unroll
                for (int j = 0; j < 8; ++j) a0[j] += a1[j];
#pragma unroll
                for (int j = 0; j < 8; ++j) {
                    a0[j] += __shfl_xor(a0[j], 4);
                    a0[j] += __shfl_xor(a0[j], 8);
                    a0[j] += __shfl_xor(a0[j], 16);
                }
                if (eg == 0) {
                    float inv = 1.0f / fmaxf((float)dv, 1.0f);
                    int cb = phase * 32 + (cg << 3);   // channel base 0..56
                    const float4* qp = (const float4*)(q + (size_t)node * 64 + cb);
                    float4 q0 = qp[0], q1 = qp[1];
                    float* d = sx + cb * LSTRIDE + nl;
                    d[0 * LSTRIDE] = fmaxf(fmaf(a0[0], inv, q0.x), 0.f);
                    d[1 * LSTRIDE] = fmaxf(fmaf(a0[1], inv, q0.y), 0.f);
                    d[2 * LSTRIDE] = fmaxf(fmaf(a0[2], inv, q0.z), 0.f);
                    d[3 * LSTRIDE] = fmaxf(fmaf(a0[3], inv, q0.w), 0.f);
                    d[4 * LSTRIDE] = fmaxf(fmaf(a0[4], inv, q1.x), 0.f);
                    d[5 * LSTRIDE] = fmaxf(fmaf(a0[5], inv, q1.y), 0.f);
                    d[6 * LSTRIDE] = fmaxf(fmaf(a0[6], inv, q1.z), 0.f);
                    d[7 * LSTRIDE] = fmaxf(fmaf(a0[7], inv, q1.w), 0.f);
                }
            }
        }
        __syncthreads();                  // phase separation (locality + tile ready)
    }
    // ---- GEMM phase: 8 groups of 128 threads = (role, c-group) x node ----
    int g = __builtin_amdgcn_readfirstlane(t >> 7);  // 0..7, wave-uniform
    int role = g & 1;                                 // 0: z (fp16), 1: r (fp32)
    int c0 = (g >> 1) * 8;                            // 0,8,16,24
    int ln = t & 127;
    int node = n0 + ln;
    const float* __restrict__ wm = role ? w2r : w2l;
    float acc[8];
    if (role) {
#pragma unroll
        for (int c = 0; c < 8; ++c) acc[c] = b2[c0 + c];
    } else {
#pragma unroll
        for (int c = 0; c < 8; ++c) acc[c] = 0.f;
    }
#pragma unroll
    for (int k = 0; k < 64; ++k) {
        float xk = sx[k * LSTRIDE + ln];
#pragma unroll
        for (int c = 0; c < 8; ++c)
            acc[c] = fmaf(xk, wm[k * 32 + c0 + c], acc[c]);
    }
    if (node >= N_NODES) return;
    if (role == 0) {
        alignas(16) __half2 hv[4];
#pragma unroll
        for (int i = 0; i < 4; ++i)
            hv[i] = __floats2half2_rn(acc[2 * i], acc[2 * i + 1]);
        *(float4*)(zh + (size_t)node * 32 + c0) = *(float4*)hv;
    } else {
        float4* op = (float4*)(r + (size_t)node * 32 + c0);
        op[0] = make_float4(acc[0], acc[1], acc[2], acc[3]);
        op[1] = make_float4(acc[4], acc[5], acc[6], acc[7]);
    }
}

// ---------------- agg2 + classifier fused (unchanged from verified R18) ----------------
__global__ __launch_bounds__(256) void k_agg2cls(const int* __restrict__ off,
                                                 const unsigned short* __restrict__ deg,
                                                 const int* __restrict__ esrc,
                                                 const __half* __restrict__ zh,
                                                 const float* __restrict__ r,
                                                 const float* __restrict__ wc1,
                                                 const float* __restrict__ bc1,
                                                 const float* __restrict__ wc2,
                                                 const float* __restrict__ bc2,
                                                 float* __restrict__ out) {
    __shared__ float sh2[16 * 33];
    __shared__ float sh3[16 * 17];
    __shared__ float swc1[512];
    __shared__ float sbc1[16];
    __shared__ float swc2[32];
    __shared__ float sbc2[2];
    int t = threadIdx.x;
    swc1[t] = wc1[t];
    swc1[t + 256] = wc1[t + 256];
    if (t < 16) sbc1[t] = bc1[t];
    if (t < 32) swc2[t] = wc2[t];
    if (t < 2)  sbc2[t] = bc2[t];

    int lane = t & 63;
    int l16 = lane & 15;
    int nl = (t >> 4) & 15;
    int node = blockIdx.x * 16 + nl;         // N % 16 == 0
    int eg = l16 >> 2;
    int cg = l16 & 3;
    int s0 = off[node];
    int dv = deg[node];
    int s1 = s0 + dv;
    float a0[8] = {0,0,0,0,0,0,0,0}, a1[8] = {0,0,0,0,0,0,0,0};
    float a2[8] = {0,0,0,0,0,0,0,0}, a3[8] = {0,0,0,0,0,0,0,0};
    for (int i = s0; i < s1; i += 16) {
        int i0 = i + eg, i1 = i + 4 + eg, i2 = i + 8 + eg, i3 = i + 12 + eg;
        if (i0 < s1) acc8(a0, *(const float4*)(zh + (size_t)esrc[i0] * 32 + (cg << 3)));
        if (i1 < s1) acc8(a1, *(const float4*)(zh + (size_t)esrc[i1] * 32 + (cg << 3)));
        if (i2 < s1) acc8(a2, *(const float4*)(zh + (size_t)esrc[i2] * 32 + (cg << 3)));
        if (i3 < s1) acc8(a3, *(const float4*)(zh + (size_t)esrc[i3] * 32 + (cg << 3)));
    }
#pragma unroll
    for (int j = 0; j < 8; ++j) a0[j] += a1[j] + (a2[j] + a3[j]);
#pragma unroll
    for (int j = 0; j < 8; ++j) {
        a0[j] += __shfl_xor(a0[j], 4);
        a0[j] += __shfl_xor(a0[j], 8);
    }
    if (eg == 0) {
        float inv = 1.0f / fmaxf((float)dv, 1.0f);
        const float4* rp = (const float4*)(r + (size_t)node * 32 + (cg << 3));
        float4 r0 = rp[0], r1 = rp[1];
        float* d = sh2 + nl * 33 + (cg << 3);
        d[0] = fmaxf(fmaf(a0[0], inv, r0.x), 0.f);
        d[1] = fmaxf(fmaf(a0[1], inv, r0.y), 0.f);
        d[2] = fmaxf(fmaf(a0[2], inv, r0.z), 0.f);
        d[3] = fmaxf(fmaf(a0[3], inv, r0.w), 0.f);
        d[4] = fmaxf(fmaf(a0[4], inv, r1.x), 0.f);
        d[5] = fmaxf(fmaf(a0[5], inv, r1.y), 0.f);
        d[6] = fmaxf(fmaf(a0[6], inv, r1.z), 0.f);
        d[7] = fmaxf(fmaf(a0[7], inv, r1.w), 0.f);
    }
    __syncthreads();
    int n = t >> 4, j = t & 15;
    float acc1 = sbc1[j];
#pragma unroll
    for (int k = 0; k < 32; ++k)
        acc1 = fmaf(sh2[n * 33 + k], swc1[k * 16 + j], acc1);
    sh3[n * 17 + j] = fmaxf(acc1, 0.f);
    __syncthreads();
    if (t < 16) {
        int nn = t;
        float o0 = sbc2[0], o1 = sbc2[1];
#pragma unroll
        for (int k = 0; k < 16; ++k) {
            float h3k = sh3[nn * 17 + k];
            o0 = fmaf(h3k, swc2[k * 2 + 0], o0);
            o1 = fmaf(h3k, swc2[k * 2 + 1], o1);
        }
        int gnode = blockIdx.x * 16 + nn;
        *(float2*)(out + (size_t)gnode * 2) = make_float2(o0, o1);
    }
}

extern "C" void kernel_launch(void* const* d_in, const int* in_sizes, int n_in,
                              void* d_out, int out_size, void* d_ws, size_t ws_size,
                              hipStream_t stream) {
    const float* x   = (const float*)d_in[0];
    const int*   ei  = (const int*)d_in[1];
    const int*   src = ei;
    const int*   dst = ei + N_EDGES;
    const float* w1l = (const float*)d_in[2];
    const float* w1r = (const float*)d_in[3];
    const float* b1  = (const float*)d_in[4];
    const float* w2l = (const float*)d_in[5];
    const float* w2r = (const float*)d_in[6];
    const float* b2  = (const float*)d_in[7];
    const float* wc1 = (const float*)d_in[8];
    const float* bc1 = (const float*)d_in[9];
    const float* wc2 = (const float*)d_in[10];
    const float* bc2 = (const float*)d_in[11];
    float* out = (float*)d_out;

    // ws layout (4B units), all regions disjoint:
    //   bincur[400] | binned[NBINS*CAP] | esrc[NBINS*CAP] | off[N] | deg[N ushort]
    //   | q[64N] | ph0[32N halfs = 16N] | ph1[32N halfs = 16N]
    //   | zh[32N halfs = 16N] | r[32N]
    int*   wi     = (int*)d_ws;
    int*   bincur = wi;
    int*   binned = wi + 400;
    int*   esrc   = binned + (size_t)NBINS * CAP;
    int*   off    = esrc + (size_t)NBINS * CAP;
    unsigned short* deg = (unsigned short*)(off + N_NODES);
    float* q      = (float*)(deg + N_NODES + (N_NODES & 1));
    float* p0f    = q + (size_t)64 * N_NODES;
    __half* ph0   = (__half*)p0f;
    float* p1f    = p0f + (size_t)16 * N_NODES;
    __half* ph1   = (__half*)p1f;
    float* zhf    = p1f + (size_t)16 * N_NODES;
    __half* zh    = (__half*)zhf;
    float* r      = zhf + (size_t)16 * N_NODES;

    // ---- bin-grouped edge list ----
    hipMemsetAsync(bincur, 0, 400 * sizeof(int), stream);
    k_binA<<<NBLK_E, 512, 0, stream>>>(src, dst, bincur, binned);

    // ---- binB + pre1 overlapped ----
    k_binB_pre1<<<NBINS + NTILE, 512, 0, stream>>>(bincur, binned, off, deg, esrc,
                                                   x, w1l, w1r, b1, ph0, ph1, q);

    // ---- layer 1 aggregation (plane-phased) + layer 2 pre-GEMM ----
    k_agg1_pre2<<<NBINS, 1024, 0, stream>>>(off, deg, esrc, ph0, ph1, q,
                                            w2l, w2r, b2, zh, r);

    // ---- layer 2 aggregation + classifier ----
    k_agg2cls<<<N_NODES / 16, 256, 0, stream>>>(off, deg, esrc, zh, r,
                                                wc1, bc1, wc2, bc2, out);
}

// Round 20
// 183.737 us; speedup vs baseline: 1.1051x; 1.1051x over previous
//
#include <hip/hip_runtime.h>
#include <hip/hip_fp16.h>

#define N_NODES 50000
#define N_EDGES 800000
#define NBINS   391          // ceil(50000/128), 128 dst nodes per bin
#define CAP     4096         // fixed per-bin capacity (mean 2048, sigma 45)
#define EPB     4096         // edges per block (binA)
#define NBLK_E  ((N_EDGES + EPB - 1) / EPB)
#define NTILE   391          // node tiles for pre1
#define LSTRIDE 129          // LDS [ch][node] stride, conflict-free

// ---------------- fused: binA (bin scatter) + pre1 (dual GEMM) ----------------
// pre1 depends only on x/weights, binA only on edge_index -> overlap them.
// blockIdx < NBLK_E: binA path; else pre1 path. LDS carved from one 33 KB pool.
__global__ __launch_bounds__(512) void k_binA_pre1(
        const int* __restrict__ src, const int* __restrict__ dst,
        int* __restrict__ bincur, int* __restrict__ binned,
        const float* __restrict__ x,
        const float* __restrict__ wl, const float* __restrict__ wr,
        const float* __restrict__ b,
        __half* __restrict__ ph, float* __restrict__ q) {
    __shared__ float smem[64 * LSTRIDE];      // 33 KB pool
    int t = threadIdx.x;
    int bb = blockIdx.x;
    if (bb < NBLK_E) {
        // ---- binA path (carve: cnt|sc|lpos|base|stage|sbin = 31.3 KB) ----
        int* cnt  = (int*)smem;               // [392]
        int* sc   = cnt + 392;                // [512]
        int* lpos = sc + 512;                 // [392]
        int* base = lpos + 392;               // [392]
        int* stage = base + 392;              // [4096]
        unsigned short* sbin = (unsigned short*)(stage + EPB);  // [4096]
        int blkbase = bb * EPB;
        int nE = min(EPB, N_EDGES - blkbase);
        for (int i = t; i < NBINS; i += 512) cnt[i] = 0;
        __syncthreads();
        int sv[8], dv[8];
#pragma unroll
        for (int k = 0; k < 8; ++k) {
            int e = blkbase + t + k * 512;
            if (e < N_EDGES) {
                sv[k] = src[e];
                dv[k] = dst[e];
                atomicAdd(&cnt[dv[k] >> 7], 1);
            } else dv[k] = -1;
        }
        __syncthreads();
        sc[t] = (t < NBINS) ? cnt[t] : 0;
        __syncthreads();
        for (int d = 1; d < 512; d <<= 1) {
            int add = (t >= d) ? sc[t - d] : 0;
            __syncthreads();
            sc[t] += add;
            __syncthreads();
        }
        for (int bi = t; bi < NBINS; bi += 512) {
            int excl = sc[bi] - cnt[bi];
            lpos[bi] = excl;
            sc[bi] = excl;
            if (cnt[bi] > 0) base[bi] = bi * CAP + atomicAdd(&bincur[bi], cnt[bi]);
        }
        __syncthreads();
#pragma unroll
        for (int k = 0; k < 8; ++k) {
            if (dv[k] >= 0) {
                int bi = dv[k] >> 7;
                int p = atomicAdd(&lpos[bi], 1);
                stage[p] = (sv[k] & 0xFFFF) | ((dv[k] & 127) << 16);
                sbin[p] = (unsigned short)bi;
            }
        }
        __syncthreads();
        for (int i = t; i < nE; i += 512) {
            int bi = sbin[i];
            int pos = base[bi] + (i - sc[bi]);
            if (pos < (bi + 1) * CAP) binned[pos] = stage[i];   // 45-sigma guard
        }
        return;
    }
    // ---- pre1 path (verified structure) ----
    float* sx = smem;
    int g0 = (bb - NBLK_E) * 128;
#pragma unroll
    for (int i = 0; i < 4; ++i) {
        int f = t + i * 512;
        int nd = f >> 4, cq = f & 15;
        int gn = g0 + nd;
        float4 v = (gn < N_NODES) ? ((const float4*)x)[(size_t)gn * 16 + cq]
                                  : make_float4(0.f, 0.f, 0.f, 0.f);
        sx[(cq * 4 + 0) * LSTRIDE + nd] = v.x;
        sx[(cq * 4 + 1) * LSTRIDE + nd] = v.y;
        sx[(cq * 4 + 2) * LSTRIDE + nd] = v.z;
        sx[(cq * 4 + 3) * LSTRIDE + nd] = v.w;
    }
    __syncthreads();
    int role = __builtin_amdgcn_readfirstlane(t >> 7);
    int wsel = role >> 1;
    int c0 = (role & 1) * 32;
    int ln = t & 127;
    int node = g0 + ln;
    const float* __restrict__ wm = wsel ? wr : wl;
    float acc[32];
    if (wsel) {
#pragma unroll
        for (int c = 0; c < 32; ++c) acc[c] = b[c0 + c];
    } else {
#pragma unroll
        for (int c = 0; c < 32; ++c) acc[c] = 0.f;
    }
#pragma unroll
    for (int k = 0; k < 64; ++k) {
        float xk = sx[k * LSTRIDE + ln];
#pragma unroll
        for (int c = 0; c < 32; ++c)
            acc[c] = fmaf(xk, wm[k * 64 + c0 + c], acc[c]);
    }
    if (node >= N_NODES) return;
    if (wsel == 0) {
        alignas(16) __half2 hv[16];
#pragma unroll
        for (int i = 0; i < 16; ++i)
            hv[i] = __floats2half2_rn(acc[2 * i], acc[2 * i + 1]);
        float4* op = (float4*)(ph + (size_t)node * 64 + c0);
#pragma unroll
        for (int i = 0; i < 4; ++i) op[i] = ((float4*)hv)[i];
    } else {
        float4* op = (float4*)(q + (size_t)node * 64 + c0);
#pragma unroll
        for (int i = 0; i < 8; ++i)
            op[i] = make_float4(acc[4 * i], acc[4 * i + 1], acc[4 * i + 2], acc[4 * i + 3]);
    }
}

// ---------------- binB: per-bin counting sort; emits off[] + deg[] ----------------
__global__ __launch_bounds__(512) void k_binB(const int* __restrict__ bincur,
                                              const int* __restrict__ binned,
                                              int* __restrict__ off,
                                              unsigned short* __restrict__ deg,
                                              int* __restrict__ esrc) {
    __shared__ int buf[CAP];
    __shared__ int cnt[128];
    __shared__ int tmp[128];
    __shared__ int cur[128];
    int bb = blockIdx.x, t = threadIdx.x;
    int n0 = bb << 7;
    int seg0 = bb * CAP;
    int n = min(bincur[bb], CAP);
    if (t < 128) cnt[t] = 0;
    __syncthreads();
    for (int i = t; i < n; i += 512) atomicAdd(&cnt[binned[seg0 + i] >> 16], 1);
    __syncthreads();
    int v = (t < 128) ? cnt[t] : 0;
    if (t < 128) tmp[t] = v;
    __syncthreads();
    int val = v;
    for (int d = 1; d < 128; d <<= 1) {
        int add = (t >= d && t < 128) ? tmp[t - d] : 0;
        __syncthreads();
        if (t < 128) { val += add; tmp[t] = val; }
        __syncthreads();
    }
    if (t < 128) {
        int excl = val - v;
        cur[t] = excl;
        int node = n0 + t;
        if (node < N_NODES) {
            off[node] = seg0 + excl;
            deg[node] = (unsigned short)v;
        }
    }
    __syncthreads();
    for (int i = t; i < n; i += 512) {
        int w = binned[seg0 + i];
        int p = atomicAdd(&cur[w >> 16], 1);
        buf[p] = w & 0xFFFF;
    }
    __syncthreads();
    for (int i = t; i < n; i += 512) esrc[seg0 + i] = buf[i];   // coalesced
}

// dequant-accumulate 16B of halfs into 8 fp32 accs
__device__ __forceinline__ void acc8(float* a, float4 rv) {
    const __half2* hp = (const __half2*)&rv;
    float2 f0 = __half22float2(hp[0]), f1 = __half22float2(hp[1]);
    float2 f2 = __half22float2(hp[2]), f3 = __half22float2(hp[3]);
    a[0] += f0.x; a[1] += f0.y; a[2] += f1.x; a[3] += f1.y;
    a[4] += f2.x; a[5] += f2.y; a[6] += f3.x; a[7] += f3.y;
}

// ---------------- fused agg1 + pre2: one block per 128-node bin (verified R18) ----------------
__global__ __launch_bounds__(1024) void k_agg1_pre2(
        const int* __restrict__ off, const unsigned short* __restrict__ deg,
        const int* __restrict__ esrc,
        const __half* __restrict__ ph, const float* __restrict__ q,
        const float* __restrict__ w2l, const float* __restrict__ w2r,
        const float* __restrict__ b2,
        __half* __restrict__ zh, float* __restrict__ r) {
    __shared__ float sx[64 * LSTRIDE];    // 33 KB h1 tile
    int t = threadIdx.x;
    int n0 = blockIdx.x << 7;
    int half = t >> 5;                    // 0..31 half-wave id
    int l32 = t & 31;
    int eg = l32 >> 3;                    // 0..3 edge slots
    int cg = l32 & 7;                     // 16B channel group
    for (int p = 0; p < 4; ++p) {
        int nl = half + 32 * p;           // 0..127
        int node = n0 + nl;
        if (node < N_NODES) {
            int s0 = off[node];
            int dv = deg[node];
            int s1 = s0 + dv;
            float a0[8] = {0,0,0,0,0,0,0,0}, a1[8] = {0,0,0,0,0,0,0,0};
            float a2[8] = {0,0,0,0,0,0,0,0}, a3[8] = {0,0,0,0,0,0,0,0};
            for (int i = s0; i < s1; i += 16) {
                int i0 = i + eg, i1 = i + 4 + eg, i2 = i + 8 + eg, i3 = i + 12 + eg;
                if (i0 < s1) acc8(a0, *(const float4*)(ph + (size_t)esrc[i0] * 64 + (cg << 3)));
                if (i1 < s1) acc8(a1, *(const float4*)(ph + (size_t)esrc[i1] * 64 + (cg << 3)));
                if (i2 < s1) acc8(a2, *(const float4*)(ph + (size_t)esrc[i2] * 64 + (cg << 3)));
                if (i3 < s1) acc8(a3, *(const float4*)(ph + (size_t)esrc[i3] * 64 + (cg << 3)));
            }
#pragma unroll
            for (int j = 0; j < 8; ++j) a0[j] += a1[j] + (a2[j] + a3[j]);
#pragma unroll
            for (int j = 0; j < 8; ++j) {
                a0[j] += __shfl_xor(a0[j], 8);
                a0[j] += __shfl_xor(a0[j], 16);
            }
            if (eg == 0) {
                float inv = 1.0f / fmaxf((float)dv, 1.0f);
                const float4* qp = (const float4*)(q + (size_t)node * 64 + (cg << 3));
                float4 q0 = qp[0], q1 = qp[1];
                float* d = sx + (cg << 3) * LSTRIDE + nl;
                d[0 * LSTRIDE] = fmaxf(fmaf(a0[0], inv, q0.x), 0.f);
                d[1 * LSTRIDE] = fmaxf(fmaf(a0[1], inv, q0.y), 0.f);
                d[2 * LSTRIDE] = fmaxf(fmaf(a0[2], inv, q0.z), 0.f);
                d[3 * LSTRIDE] = fmaxf(fmaf(a0[3], inv, q0.w), 0.f);
                d[4 * LSTRIDE] = fmaxf(fmaf(a0[4], inv, q1.x), 0.f);
                d[5 * LSTRIDE] = fmaxf(fmaf(a0[5], inv, q1.y), 0.f);
                d[6 * LSTRIDE] = fmaxf(fmaf(a0[6], inv, q1.z), 0.f);
                d[7 * LSTRIDE] = fmaxf(fmaf(a0[7], inv, q1.w), 0.f);
            }
        }
    }
    __syncthreads();
    // ---- GEMM phase: 8 groups of 128 threads = (role, c-group) x node ----
    int g = __builtin_amdgcn_readfirstlane(t >> 7);  // 0..7, wave-uniform
    int role = g & 1;                                 // 0: z (fp16), 1: r (fp32)
    int c0 = (g >> 1) * 8;                            // 0,8,16,24
    int ln = t & 127;
    int node = n0 + ln;
    const float* __restrict__ wm = role ? w2r : w2l;
    float acc[8];
    if (role) {
#pragma unroll
        for (int c = 0; c < 8; ++c) acc[c] = b2[c0 + c];
    } else {
#pragma unroll
        for (int c = 0; c < 8; ++c) acc[c] = 0.f;
    }
#pragma unroll
    for (int k = 0; k < 64; ++k) {
        float xk = sx[k * LSTRIDE + ln];
#pragma unroll
        for (int c = 0; c < 8; ++c)
            acc[c] = fmaf(xk, wm[k * 32 + c0 + c], acc[c]);
    }
    if (node >= N_NODES) return;
    if (role == 0) {
        alignas(16) __half2 hv[4];
#pragma unroll
        for (int i = 0; i < 4; ++i)
            hv[i] = __floats2half2_rn(acc[2 * i], acc[2 * i + 1]);
        *(float4*)(zh + (size_t)node * 32 + c0) = *(float4*)hv;
    } else {
        float4* op = (float4*)(r + (size_t)node * 32 + c0);
        op[0] = make_float4(acc[0], acc[1], acc[2], acc[3]);
        op[1] = make_float4(acc[4], acc[5], acc[6], acc[7]);
    }
}

// ---------------- agg2 + classifier fused (verified R18) ----------------
__global__ __launch_bounds__(256) void k_agg2cls(const int* __restrict__ off,
                                                 const unsigned short* __restrict__ deg,
                                                 const int* __restrict__ esrc,
                                                 const __half* __restrict__ zh,
                                                 const float* __restrict__ r,
                                                 const float* __restrict__ wc1,
                                                 const float* __restrict__ bc1,
                                                 const float* __restrict__ wc2,
                                                 const float* __restrict__ bc2,
                                                 float* __restrict__ out) {
    __shared__ float sh2[16 * 33];
    __shared__ float sh3[16 * 17];
    __shared__ float swc1[512];
    __shared__ float sbc1[16];
    __shared__ float swc2[32];
    __shared__ float sbc2[2];
    int t = threadIdx.x;
    swc1[t] = wc1[t];
    swc1[t + 256] = wc1[t + 256];
    if (t < 16) sbc1[t] = bc1[t];
    if (t < 32) swc2[t] = wc2[t];
    if (t < 2)  sbc2[t] = bc2[t];

    int lane = t & 63;
    int l16 = lane & 15;
    int nl = (t >> 4) & 15;
    int node = blockIdx.x * 16 + nl;         // N % 16 == 0
    int eg = l16 >> 2;
    int cg = l16 & 3;
    int s0 = off[node];
    int dv = deg[node];
    int s1 = s0 + dv;
    float a0[8] = {0,0,0,0,0,0,0,0}, a1[8] = {0,0,0,0,0,0,0,0};
    float a2[8] = {0,0,0,0,0,0,0,0}, a3[8] = {0,0,0,0,0,0,0,0};
    for (int i = s0; i < s1; i += 16) {
        int i0 = i + eg, i1 = i + 4 + eg, i2 = i + 8 + eg, i3 = i + 12 + eg;
        if (i0 < s1) acc8(a0, *(const float4*)(zh + (size_t)esrc[i0] * 32 + (cg << 3)));
        if (i1 < s1) acc8(a1, *(const float4*)(zh + (size_t)esrc[i1] * 32 + (cg << 3)));
        if (i2 < s1) acc8(a2, *(const float4*)(zh + (size_t)esrc[i2] * 32 + (cg << 3)));
        if (i3 < s1) acc8(a3, *(const float4*)(zh + (size_t)esrc[i3] * 32 + (cg << 3)));
    }
#pragma unroll
    for (int j = 0; j < 8; ++j) a0[j] += a1[j] + (a2[j] + a3[j]);
#pragma unroll
    for (int j = 0; j < 8; ++j) {
        a0[j] += __shfl_xor(a0[j], 4);
        a0[j] += __shfl_xor(a0[j], 8);
    }
    if (eg == 0) {
        float inv = 1.0f / fmaxf((float)dv, 1.0f);
        const float4* rp = (const float4*)(r + (size_t)node * 32 + (cg << 3));
        float4 r0 = rp[0], r1 = rp[1];
        float* d = sh2 + nl * 33 + (cg << 3);
        d[0] = fmaxf(fmaf(a0[0], inv, r0.x), 0.f);
        d[1] = fmaxf(fmaf(a0[1], inv, r0.y), 0.f);
        d[2] = fmaxf(fmaf(a0[2], inv, r0.z), 0.f);
        d[3] = fmaxf(fmaf(a0[3], inv, r0.w), 0.f);
        d[4] = fmaxf(fmaf(a0[4], inv, r1.x), 0.f);
        d[5] = fmaxf(fmaf(a0[5], inv, r1.y), 0.f);
        d[6] = fmaxf(fmaf(a0[6], inv, r1.z), 0.f);
        d[7] = fmaxf(fmaf(a0[7], inv, r1.w), 0.f);
    }
    __syncthreads();
    int n = t >> 4, j = t & 15;
    float acc1 = sbc1[j];
#pragma unroll
    for (int k = 0; k < 32; ++k)
        acc1 = fmaf(sh2[n * 33 + k], swc1[k * 16 + j], acc1);
    sh3[n * 17 + j] = fmaxf(acc1, 0.f);
    __syncthreads();
    if (t < 16) {
        int nn = t;
        float o0 = sbc2[0], o1 = sbc2[1];
#pragma unroll
        for (int k = 0; k < 16; ++k) {
            float h3k = sh3[nn * 17 + k];
            o0 = fmaf(h3k, swc2[k * 2 + 0], o0);
            o1 = fmaf(h3k, swc2[k * 2 + 1], o1);
        }
        int gnode = blockIdx.x * 16 + nn;
        *(float2*)(out + (size_t)gnode * 2) = make_float2(o0, o1);
    }
}

extern "C" void kernel_launch(void* const* d_in, const int* in_sizes, int n_in,
                              void* d_out, int out_size, void* d_ws, size_t ws_size,
                              hipStream_t stream) {
    const float* x   = (const float*)d_in[0];
    const int*   ei  = (const int*)d_in[1];
    const int*   src = ei;
    const int*   dst = ei + N_EDGES;
    const float* w1l = (const float*)d_in[2];
    const float* w1r = (const float*)d_in[3];
    const float* b1  = (const float*)d_in[4];
    const float* w2l = (const float*)d_in[5];
    const float* w2r = (const float*)d_in[6];
    const float* b2  = (const float*)d_in[7];
    const float* wc1 = (const float*)d_in[8];
    const float* bc1 = (const float*)d_in[9];
    const float* wc2 = (const float*)d_in[10];
    const float* bc2 = (const float*)d_in[11];
    float* out = (float*)d_out;

    // ws layout (4B units), all regions disjoint:
    //   bincur[400] | binned[NBINS*CAP] | esrc[NBINS*CAP] | off[N] | deg[N ushort]
    //   | q[64N] | ph[64N halfs = 32N] | zh[32N halfs = 16N] | r[32N]
    int*   wi     = (int*)d_ws;
    int*   bincur = wi;
    int*   binned = wi + 400;
    int*   esrc   = binned + (size_t)NBINS * CAP;
    int*   off    = esrc + (size_t)NBINS * CAP;
    unsigned short* deg = (unsigned short*)(off + N_NODES);
    float* q      = (float*)(deg + N_NODES + (N_NODES & 1));
    float* phf    = q + (size_t)64 * N_NODES;
    __half* ph    = (__half*)phf;
    float* zhf    = phf + (size_t)32 * N_NODES;
    __half* zh    = (__half*)zhf;
    float* r      = zhf + (size_t)16 * N_NODES;

    // ---- binA + pre1 overlapped (both depend only on inputs) ----
    hipMemsetAsync(bincur, 0, 400 * sizeof(int), stream);
    k_binA_pre1<<<NBLK_E + NTILE, 512, 0, stream>>>(src, dst, bincur, binned,
                                                    x, w1l, w1r, b1, ph, q);

    // ---- binB (counting sort -> off/deg/esrc) ----
    k_binB<<<NBINS, 512, 0, stream>>>(bincur, binned, off, deg, esrc);

    // ---- layer 1 aggregation + layer 2 pre-GEMM (fused, h1 stays in LDS) ----
    k_agg1_pre2<<<NBINS, 1024, 0, stream>>>(off, deg, esrc, ph, q,
                                            w2l, w2r, b2, zh, r);

    // ---- layer 2 aggregation + classifier ----
    k_agg2cls<<<N_NODES / 16, 256, 0, stream>>>(off, deg, esrc, zh, r,
                                                wc1, bc1, wc2, bc2, out);
}